// Round 9
// baseline (415.157 us; speedup 1.0000x reference)
//
#include <hip/hip_runtime.h>
#include <math.h>

// MoE FFN, routed (top-2 pair-grouped).
//   Tp (G1 out / G2 A): per tile, 8 sequential 16-KB BLK blocks
//       BLK = [128 rows][64 k], elem(r,k) at r*64+(((k>>3)^(r&7))<<3|(k&7)).
//       kt = esel*4 + nc*2 + kh  (rank = (nc*2+kh)*64 + klocal).
//   w2p: BLK blocks [nb128(32)][e(8)][rb(4)], rows = f-local, k = rank-local.
//   Hb (G2 out / G3 A): plain row-major [tok][4096].
//   G1: 64x128 BK=128 (2-barrier main loop; epilogue -> BLKs)
//   G2: round-13: r11 kernel + outer s-loop (8 nb-steps -> 64-kt stream).
//       Diagnosis: all short-loop G2s (8 kt) spend most time in pipeline
//       fill/drain + exposed DMA latency (72->112 us monotone in blocks/CU;
//       G3's identical skeleton at 64 kt is fast). Block = 64 rows x 1024
//       cols; per s: re-prologue, verbatim r11 8-kt counted-vmcnt loop,
//       epilogue into retired B buf. A re-staged per s (L2-hot). 536
//       active blocks at 2/CU -> 1.05 generations. Linear bid decode
//       (XCD map of r12 hurt: 112 us).
//   G3: round-8 (verified): BM=256 BN=128 BK=64, 8 waves, 3-stage pipeline.
// Image swizzle (G1 inputs only): r*128 + (((k>>3)^(r&15))<<3 | (k&7)).

using short8  = __attribute__((ext_vector_type(8))) short;
using floatx4 = __attribute__((ext_vector_type(4))) float;
typedef unsigned short bf16_t;

#define TOK   8192
#define HDIM  1024
#define RDIM  256
#define FDIM  4096
#define NEXP  8
#define MAXTILES 96
#define MAXSLOTS 16384
#define IMG   16384

__device__ __forceinline__ bf16_t f2bf(float f) {
  union { float f; unsigned u; } a; a.f = f;
  unsigned u = a.u;
  return (bf16_t)((u + 0x7FFFu + ((u >> 16) & 1u)) >> 16);  // RNE
}

__device__ __forceinline__ float gelu_erf(float v) {
  return 0.5f * v * (1.0f + erff(v * 0.70710678118654752f));
}

__device__ __forceinline__ void gload16(const void* g, void* l) {
  __builtin_amdgcn_global_load_lds(
      (const __attribute__((address_space(1))) void*)g,
      (__attribute__((address_space(3))) void*)l, 16, 0, 0);
}

__device__ __forceinline__ int swz_off(int r, int kl) {
  return r * 128 + ((((kl >> 3) ^ (r & 15)) << 3) | (kl & 7));
}

// ---------------------------------------------------------------- packing

__device__ __forceinline__ void pack_tile_body(const float* __restrict__ src,
                                               size_t kStride,
                                               bf16_t* __restrict__ img) {
  __shared__ bf16_t lim[IMG];
  const int tid = threadIdx.x;
  const int rr = tid & 127, half = tid >> 7;
  for (int kl = half; kl < 128; kl += 2)
    lim[swz_off(rr, kl)] = f2bf(src[(size_t)kl * kStride + rr]);
  __syncthreads();
  const int4* s4 = (const int4*)lim;
  int4* d4 = (int4*)img;
#pragma unroll
  for (int i = 0; i < 8; i++) d4[tid + i * 256] = s4[tid + i * 256];
}

// w1p [e][nc][kb]: rows = rank nc*128+rr, k = h kb*128+kl  (G1 B operand)
__global__ void pack_w1(const float* __restrict__ w1, bf16_t* __restrict__ w1p) {
  const int img = blockIdx.x;
  const int e = img >> 4, nc = (img >> 3) & 1, kb = img & 7;
  pack_tile_body(w1 + (size_t)e * 1024 * 256 + (size_t)kb * 128 * 256 + nc * 128,
                 256, w1p + (size_t)img * IMG);
}

// w2p: BLK blocks [nb128][e][rb]: 128 f-rows x 64 rank, G3-style swizzle.
__global__ void pack_w2(const float* __restrict__ w2, bf16_t* __restrict__ w2p) {
  __shared__ bf16_t lim[8192];
  const int img = blockIdx.x;                // nb*32 + e*4 + rb
  const int nb = img >> 5, e = (img >> 2) & 7, rb = img & 3;
  const float* src = w2 + (size_t)e * 256 * 4096 + (size_t)rb * 64 * 4096 + nb * 128;
  const int tid = threadIdx.x;
  const int row = tid & 127, k0 = tid >> 7;  // k0 = 0/1
  for (int k = k0; k < 64; k += 2)
    lim[row * 64 + ((((k >> 3) ^ (row & 7)) << 3) | (k & 7))] =
        f2bf(src[(size_t)k * 4096 + row]);
  __syncthreads();
  const int4* s4 = (const int4*)lim;
  int4* d4 = (int4*)(w2p + (size_t)img * 8192);
#pragma unroll
  for (int i = 0; i < 4; i++) d4[tid + i * 256] = s4[tid + i * 256];
}

// transpose+convert (for lin2_w -> ltw[h][f], row-major bf16)
__global__ void tcvt(const float* __restrict__ in, bf16_t* __restrict__ out,
                     int cols, size_t inSlice, size_t ldo,
                     int outRowStep, int outColStep) {
  __shared__ float tile[64][65];
  const int z  = blockIdx.z;
  const float* src = in + (size_t)z * inSlice;
  const int c0 = blockIdx.x * 64;
  const int r0 = blockIdx.y * 64;
  const int tx = threadIdx.x;
  const int ty = threadIdx.y;
#pragma unroll
  for (int i = 0; i < 64; i += 4)
    tile[ty + i][tx] = src[(size_t)(r0 + ty + i) * cols + (c0 + tx)];
  __syncthreads();
#pragma unroll
  for (int i = 0; i < 64; i += 4) {
    float v = tile[tx][ty + i];
    out[((size_t)(c0 + ty + i) + (size_t)z * outRowStep) * ldo +
        (size_t)z * outColStep + (r0 + tx)] = f2bf(v);
  }
}

// ---------------------------------------------------------------- routing

__global__ void router_kernel(const float* __restrict__ x,
                              const float* __restrict__ rw,
                              const float* __restrict__ rb,
                              int* __restrict__ gid_tok,
                              float2* __restrict__ tokscale,
                              bf16_t* __restrict__ xb) {
  const int token = blockIdx.x * 4 + (threadIdx.x >> 6);
  const int lane  = threadIdx.x & 63;
  const float* xr = x + (size_t)token * HDIM;
  bf16_t* xbr = xb + (size_t)token * HDIM;

  double acc[NEXP];
#pragma unroll
  for (int e = 0; e < NEXP; e++) acc[e] = 0.0;
  for (int h = lane; h < HDIM; h += 64) {
    const float xf = xr[h];
    xbr[h] = f2bf(xf);
    const double xv = (double)xf;
    const float* wr = rw + (size_t)h * NEXP;
#pragma unroll
    for (int e = 0; e < NEXP; e++) acc[e] += xv * (double)wr[e];
  }
#pragma unroll
  for (int off = 32; off > 0; off >>= 1) {
#pragma unroll
    for (int e = 0; e < NEXP; e++) acc[e] += __shfl_xor(acc[e], off, 64);
  }
  double lg[NEXP];
#pragma unroll
  for (int e = 0; e < NEXP; e++) lg[e] = acc[e] + (double)rb[e];

  double mx = lg[0];
#pragma unroll
  for (int e = 1; e < NEXP; e++) mx = fmax(mx, lg[e]);
  double p[NEXP]; double den = 0.0;
#pragma unroll
  for (int e = 0; e < NEXP; e++) { p[e] = exp(lg[e] - mx); den += p[e]; }

  int i1 = 0;
#pragma unroll
  for (int e = 1; e < NEXP; e++) if (lg[e] > lg[i1]) i1 = e;
  int i2 = (i1 == 0) ? 1 : 0;
#pragma unroll
  for (int e = 0; e < NEXP; e++)
    if (e != i1 && e != i2 && lg[e] > lg[i2]) i2 = e;

  if (lane == 0) {
    const int elo = min(i1, i2), ehi = max(i1, i2);
    gid_tok[token] = elo * 8 + ehi;
    tokscale[token] = make_float2((float)(p[elo] / den), (float)(p[ehi] / den));
  }
}

__global__ void build_tiles(const int* __restrict__ gid_tok,
                            int* __restrict__ ctrl,
                            int* __restrict__ tok_of_slot,
                            float2* __restrict__ scale_of_slot) {
  __shared__ int hist[64], ntl[64];
  const int t = threadIdx.x;
  for (int i = t; i < MAXSLOTS; i += 256) {
    tok_of_slot[i] = -1;
    scale_of_slot[i] = make_float2(0.f, 0.f);
  }
  if (t < 64) hist[t] = 0;
  __syncthreads();
  for (int i = t; i < TOK; i += 256) atomicAdd(&hist[gid_tok[i]], 1);
  __syncthreads();
  if (t < 64) ntl[t] = (hist[t] + 127) >> 7;
  __syncthreads();
  if (t < 64) {
    int slot0 = 0, tile0 = 0;
    for (int g = 0; g < t; g++) { slot0 += ntl[g] << 7; tile0 += ntl[g]; }
    ctrl[64 + t] = 0;
    ctrl[128 + t] = slot0;
    const int nt = ntl[t], c = hist[t];
    for (int i = 0; i < nt; i++) {
      ctrl[256 + (tile0 + i) * 3 + 0] = t;
      ctrl[256 + (tile0 + i) * 3 + 1] = slot0 + i * 128;
      ctrl[256 + (tile0 + i) * 3 + 2] = min(128, c - i * 128);
    }
    if (t == 63) ctrl[192] = tile0 + nt;
  }
}

__global__ void scatter_tokens(const int* __restrict__ gid_tok,
                               const float2* __restrict__ tokscale,
                               int* __restrict__ ctrl,
                               int* __restrict__ tok_of_slot,
                               float2* __restrict__ scale_of_slot) {
  const int t = blockIdx.x * 256 + threadIdx.x;
  const int g = gid_tok[t];
  const int pos = atomicAdd(&ctrl[64 + g], 1);
  const int slot = ctrl[128 + g] + pos;
  tok_of_slot[slot] = t;
  scale_of_slot[slot] = tokscale[t];
}

// ---------------------------------------------------------------- G1
// 64x128 tile, BK=128. Main loop unchanged. Epilogue writes Tp BLKs:
// kt = n*2 + (c>>6); elem at BLKbase + row*64 + (((c>>3&7)^(row&7))<<3|(c&7)).
__global__ __launch_bounds__(256)
void gemm_g1(const bf16_t* __restrict__ xb, const bf16_t* __restrict__ w1p,
             bf16_t* __restrict__ Tp, const int* __restrict__ ctrl,
             const int* __restrict__ tok_of_slot,
             const float2* __restrict__ scale_of_slot) {
  const int b = blockIdx.x;
  const int tile = b >> 3, mh = (b >> 2) & 1, n = b & 3;
  if (tile >= ctrl[192]) return;
  const int nrows = ctrl[256 + tile * 3 + 2];
  if (mh && nrows <= 64) return;
  __shared__ bf16_t As[64 * 128];
  __shared__ bf16_t Bs[128 * 128];
  const int gid   = ctrl[256 + tile * 3];
  const int slot0 = ctrl[256 + tile * 3 + 1];
  const int e = (n < 2) ? (gid >> 3) : (gid & 7);
  const int nc = n & 1;
  const int tid = threadIdx.x, lane = tid & 63, w = tid >> 6;
  const int wm = (w & 1) * 32, wn = (w >> 1) * 64;
  const int l16 = lane & 15, quad = lane >> 4;

  floatx4 acc[2][4];
  const floatx4 zero = {0.f, 0.f, 0.f, 0.f};
#pragma unroll
  for (int i = 0; i < 2; i++)
#pragma unroll
    for (int j = 0; j < 4; j++) acc[i][j] = zero;

  int toks[4];
  int rowAs[4];
#pragma unroll
  for (int i = 0; i < 4; i++) {
    rowAs[i] = w * 16 + i * 4 + (lane >> 4);
    int tk = tok_of_slot[slot0 + mh * 64 + rowAs[i]];
    toks[i] = (tk < 0) ? 0 : tk;
  }
  const bf16_t* bimg = w1p + (size_t)(e * 16 + nc * 8) * IMG;
  bf16_t* lA = As + w * 2048;
  bf16_t* lB = Bs + w * 4096;

  for (int kb = 0; kb < 8; kb++) {
    __syncthreads();
#pragma unroll
    for (int i = 0; i < 4; i++) {
      const int gq = (lane & 15) ^ (rowAs[i] & 15);
      gload16(xb + (size_t)toks[i] * HDIM + kb * 128 + gq * 8, lA + i * 512);
    }
#pragma unroll
    for (int i = 0; i < 8; i++)
      gload16(bimg + (size_t)kb * IMG + w * 4096 + i * 512 + lane * 8, lB + i * 512);
    __syncthreads();
#pragma unroll
    for (int s = 0; s < 4; s++) {
      const int pg = ((s * 4 + quad) ^ l16) << 3;
      short8 af[2], bfr[4];
#pragma unroll
      for (int i = 0; i < 2; i++)
        af[i] = *(const short8*)&As[(wm + i * 16 + l16) * 128 + pg];
#pragma unroll
      for (int i = 0; i < 4; i++)
        bfr[i] = *(const short8*)&Bs[(wn + i * 16 + l16) * 128 + pg];
#pragma unroll
      for (int mi = 0; mi < 2; mi++)
#pragma unroll
        for (int ni = 0; ni < 4; ni++)
          acc[mi][ni] = __builtin_amdgcn_mfma_f32_16x16x32_bf16(
              af[mi], bfr[ni], acc[mi][ni], 0, 0, 0);
    }
  }

  // epilogue: scaled bf16 -> BLK-layout LDS -> two 8-KB chunks to Tp
  __syncthreads();
#pragma unroll
  for (int mi = 0; mi < 2; mi++) {
#pragma unroll
    for (int r = 0; r < 4; r++) {
      const int rloc = wm + mi * 16 + quad * 4 + r;
      const float2 sc = scale_of_slot[slot0 + mh * 64 + rloc];
      const float s = (n < 2) ? sc.x : sc.y;
#pragma unroll
      for (int ni = 0; ni < 4; ni++) {
        const int c = wn + ni * 16 + l16;
        As[((c >> 6) << 12) + rloc * 64 +
           (((((c >> 3) & 7) ^ (rloc & 7)) << 3) | (c & 7))] =
            f2bf(acc[mi][ni][r] * s);
      }
    }
  }
  __syncthreads();
  {
    const int4* s4 = (const int4*)As;
    int4* d0 = (int4*)(Tp + (size_t)tile * 65536 + (size_t)(n * 2) * 8192 + mh * 4096);
    int4* d1 = (int4*)(Tp + (size_t)tile * 65536 + (size_t)(n * 2 + 1) * 8192 + mh * 4096);
    d0[tid] = s4[tid];
    d0[tid + 256] = s4[tid + 256];
    d1[tid] = s4[tid + 512];
    d1[tid + 256] = s4[tid + 768];
  }
}

// ---------------------------------------------------------------- G2
// Round-13: r11 kernel + outer s-loop. Block = (half-tile, colq) covering
// 64 rows x 1024 cols as 8 nb-steps; per s: re-prologue (2-kt stage), the
// r11 8-kt counted-vmcnt loop (verbatim), epilogue into retired B buf 0,
// acc reset. A (64 KB) re-staged per s from identical addresses (L2-hot
// after s=0). 256 thr = 4 waves (2Mx2N, 32x64/wave), triple-buffer 72 KB
// -> 2 blocks/CU; ~536 active blocks -> 1.05 dispatch generations.
#define MFMA_BF16(a, b, c) __builtin_amdgcn_mfma_f32_16x16x32_bf16(a, b, c, 0, 0, 0)

__global__ __launch_bounds__(256, 2)
void gemm_g2(const bf16_t* __restrict__ Tp, const bf16_t* __restrict__ w2p,
             bf16_t* __restrict__ Hb, const int* __restrict__ ctrl,
             const int* __restrict__ tok_of_slot) {
  __shared__ bf16_t As[3 * 4096];     // 24 KB
  __shared__ bf16_t Bs[3 * 8192];     // 48 KB
  const int b = blockIdx.x;
  const int colq = b & 3, ht = b >> 2;
  const int tile = ht >> 1, mh = ht & 1;
  if (tile >= ctrl[192]) return;
  const int nrows = ctrl[256 + tile * 3 + 2];
  if (mh && nrows <= 64) return;
  const int gid   = ctrl[256 + tile * 3];
  const int slot0 = ctrl[256 + tile * 3 + 1];
  const int elo = gid >> 3, ehi = gid & 7;

  const int tid = threadIdx.x, lane = tid & 63, w = tid >> 6;
  const int l16 = lane & 15, quad = (lane >> 4) & 3;
  const int WM = (w & 1) * 32, WN = (w >> 1) * 64;
  const int so = w << 9;              // wave-uniform LDS slot (512 elems)

  int aoff[2], boff[4];
#pragma unroll
  for (int mi = 0; mi < 2; mi++) {
    const int r = WM + mi * 16 + l16;
    aoff[mi] = r * 64 + ((quad ^ (r & 7)) << 3);
  }
#pragma unroll
  for (int ni = 0; ni < 4; ni++) {
    const int r = WN + ni * 16 + l16;
    boff[ni] = r * 64 + ((quad ^ (r & 7)) << 3);
  }

  const bf16_t* Abase = Tp + (size_t)tile * 65536 + mh * 4096;
  const floatx4 zero = {0.f, 0.f, 0.f, 0.f};

#pragma unroll 1
  for (int s = 0; s < 8; ++s) {
    const int nb = colq * 8 + s;

    floatx4 acc[2][4];
#pragma unroll
    for (int mi = 0; mi < 2; mi++)
#pragma unroll
      for (int ni = 0; ni < 4; ni++) acc[mi][ni] = zero;

    const bf16_t* Ac = As;             const bf16_t* Bc = Bs;
    const bf16_t* An = As + 4096;      const bf16_t* Bn = Bs + 8192;
    bf16_t*       Ag = As + 8192;      bf16_t*       Bg = Bs + 16384;

    auto stage = [&](int ktS, bf16_t* Ad, bf16_t* Bd) {
      const int e_  = (ktS < 4) ? elo : ehi;
      const int rb_ = ktS & 3;
      const bf16_t* as_ = Abase + (size_t)ktS * 8192 + tid * 8;
      const bf16_t* b0_ = w2p + (size_t)(nb * 32 + e_ * 4 + rb_) * 8192 + tid * 8;
      gload16(as_,        Ad + so);
      gload16(as_ + 2048, Ad + so + 2048);
      gload16(b0_,        Bd + so);
      gload16(b0_ + 2048, Bd + so + 2048);
      gload16(b0_ + 4096, Bd + so + 4096);
      gload16(b0_ + 6144, Bd + so + 6144);
    };

    // -------- per-s prologue: stage kt=0 -> buf0, kt=1 -> buf1
    stage(0, (bf16_t*)As, (bf16_t*)Bs);
    stage(1, (bf16_t*)As + 4096, (bf16_t*)Bs + 8192);
    asm volatile("s_waitcnt vmcnt(6)" ::: "memory");   // kt0 landed
    __builtin_amdgcn_s_barrier();

    short8 rA[2], rB[4], sA[2], sB[4];
#pragma unroll
    for (int mi = 0; mi < 2; mi++) rA[mi] = *(const short8*)&Ac[aoff[mi]];
#pragma unroll
    for (int ni = 0; ni < 4; ni++) rB[ni] = *(const short8*)&Bc[boff[ni]];

#pragma unroll 1
    for (int kt = 0; kt < 8; ++kt) {
      // 1. stage buf[kt+2]
      if (kt < 6) stage(kt + 2, Ag, Bg);
      // 2. regs s* <- slice 2kt+1 (kk=1)
#pragma unroll
      for (int mi = 0; mi < 2; mi++) sA[mi] = *(const short8*)&Ac[aoff[mi] ^ 32];
#pragma unroll
      for (int ni = 0; ni < 4; ni++) sB[ni] = *(const short8*)&Bc[boff[ni] ^ 32];
      __builtin_amdgcn_sched_barrier(0);
      // 4. MFMA slice 2kt
      __builtin_amdgcn_s_setprio(1);
#pragma unroll
      for (int mi = 0; mi < 2; mi++)
#pragma unroll
        for (int ni = 0; ni < 4; ni++)
          acc[mi][ni] = MFMA_BF16(rA[mi], rB[ni], acc[mi][ni]);
      __builtin_amdgcn_s_setprio(0);
      // 5. retire this wave's reads of buf[kt]
      asm volatile("s_waitcnt lgkmcnt(0)" ::: "memory");
      __builtin_amdgcn_sched_barrier(0);
      // 6. buf[kt+1] staged (kt+2's 6 loads stay in flight)
      if (kt < 6)       asm volatile("s_waitcnt vmcnt(6)" ::: "memory");
      else if (kt == 6) asm volatile("s_waitcnt vmcnt(0)" ::: "memory");
      // 7. raw barrier
      if (kt < 7) __builtin_amdgcn_s_barrier();
      __builtin_amdgcn_sched_barrier(0);
      // 8. regs r* <- slice 2kt+2 (kk=0, buf[kt+1])
      if (kt < 7) {
#pragma unroll
        for (int mi = 0; mi < 2; mi++) rA[mi] = *(const short8*)&An[aoff[mi]];
#pragma unroll
        for (int ni = 0; ni < 4; ni++) rB[ni] = *(const short8*)&Bn[boff[ni]];
      }
      __builtin_amdgcn_sched_barrier(0);
      // 9. MFMA slice 2kt+1
      __builtin_amdgcn_s_setprio(1);
#pragma unroll
      for (int mi = 0; mi < 2; mi++)
#pragma unroll
        for (int ni = 0; ni < 4; ni++)
          acc[mi][ni] = MFMA_BF16(sA[mi], sB[ni], acc[mi][ni]);
      __builtin_amdgcn_s_setprio(0);
      // 10. rotate
      const bf16_t* ta = Ac; Ac = An; An = Ag; Ag = (bf16_t*)ta;
      const bf16_t* tb = Bc; Bc = Bn; Bn = Bg; Bg = (bf16_t*)tb;
    }

    // -------- epilogue s: gelu -> XOR-slot LDS [64][128] -> token scatter
    __syncthreads();
#pragma unroll
    for (int mi = 0; mi < 2; mi++)
#pragma unroll
      for (int ni = 0; ni < 4; ni++) {
#pragma unroll
        for (int r = 0; r < 4; r++) {
          const int row = WM + mi * 16 + quad * 4 + r;
          const int col = WN + ni * 16 + l16;
          Bs[row * 128 + (col ^ (((row >> 2) & 3) << 4))] =
              f2bf(gelu_erf(acc[mi][ni][r]));
        }
      }
    __syncthreads();
    const int4* s4 = (const int4*)Bs;
#pragma unroll
    for (int j4 = 0; j4 < 4; j4++) {
      const int chunk = tid + j4 * 256;
      const int row = chunk >> 4, off = chunk & 15;
      const int tok = tok_of_slot[slot0 + mh * 64 + row];
      if (tok >= 0)
        *(int4*)(Hb + (size_t)tok * FDIM + nb * 128 + off * 8) =
            s4[(row << 4) | (off ^ (((row >> 2) & 3) << 1))];
    }
    __syncthreads();   // scatter reads done before next s overwrites bufs
  }
}

// ---------------------------------------------------------------- G3
// Round-8 (verified): BM=256 BN=128 BK=64, 512 threads = 8 waves (4Mx2N),
// 64x64/wave, 3-stage pipeline, counted vmcnt(6), triple-buffer 144 KB.
__global__ __launch_bounds__(512, 1)
void gemm_g3(const bf16_t* __restrict__ Hb, const bf16_t* __restrict__ ltw,
             float* __restrict__ out, const float* __restrict__ bias) {
  __shared__ bf16_t As[3 * 256 * 64];   // 96 KB
  __shared__ bf16_t Bs[3 * 128 * 64];   // 48 KB

  const int i = blockIdx.x;
  const int xcd = i & 7, j = i >> 3;
  const int m0 = (xcd * 4 + (j >> 3)) * 256;
  const int n0 = (j & 7) * 128;

  const int tid  = threadIdx.x;
  const int lane = tid & 63;
  const int w    = tid >> 6;
  const int l16  = lane & 15;
  const int quad = (lane >> 4) & 3;
  const int WM   = (w & 3) * 64;
  const int WN   = (w >> 2) * 64;

  const int srow = tid >> 3;
  const int sswz = ((tid & 7) ^ (srow & 7)) << 3;
  const bf16_t* ga[4];
  const bf16_t* gb[2];
#pragma unroll
  for (int c = 0; c < 4; c++)
    ga[c] = Hb + (size_t)(m0 + c * 64 + srow) * FDIM + sswz;
#pragma unroll
  for (int c = 0; c < 2; c++)
    gb[c] = ltw + (size_t)(n0 + c * 64 + srow) * FDIM + sswz;
  const int sd = w * 512;

  int aoff[4], boff[4];
#pragma unroll
  for (int mi = 0; mi < 4; mi++) {
    const int r = WM + mi * 16 + l16;
    aoff[mi] = r * 64 + (((((r >> 2) & 1) << 2) | (quad ^ (r & 3))) << 3);
  }
#pragma unroll
  for (int ni = 0; ni < 4; ni++) {
    const int r = WN + ni * 16 + l16;
    boff[ni] = r * 64 + (((((r >> 2) & 1) << 2) | (quad ^ (r & 3))) << 3);
  }

  floatx4 acc[4][4];
  const floatx4 zero = {0.f, 0.f, 0.f, 0.f};
#pragma unroll
  for (int mi = 0; mi < 4; mi++)
#pragma unroll
    for (int ni = 0; ni < 4; ni++) acc[mi][ni] = zero;

  const bf16_t* Ac = As;              const bf16_t* Bc = Bs;
  const bf16_t* An = As + 16384;      const bf16_t* Bn = Bs + 8192;
  bf16_t*       Ag = As + 32768;      bf16_t*       Bg = Bs + 16384;

#pragma unroll
  for (int c = 0; c < 4; c++) { gload16(ga[c], (bf16_t*)As + c * 4096 + sd); ga[c] += 64; }
#pragma unroll
  for (int c = 0; c < 2; c++) { gload16(gb[c], (bf16_t*)Bs + c * 4096 + sd); gb[c] += 64; }
#pragma unroll
  for (int c = 0; c < 4; c++) { gload16(ga[c], (bf16_t*)As + 16384 + c * 4096 + sd); ga[c] += 64; }
#pragma unroll
  for (int c = 0; c < 2; c++) { gload16(gb[c], (bf16_t*)Bs + 8192 + c * 4096 + sd); gb[c] += 64; }
  asm volatile("s_waitcnt vmcnt(6)" ::: "memory");
  __builtin_amdgcn_s_barrier();

  short8 rA[4], rB[4], sA[4], sB[4];
#pragma unroll
  for (int mi = 0; mi < 4; mi++) rA[mi] = *(const short8*)&Ac[aoff[mi]];
#pragma unroll
  for (int ni = 0; ni < 4; ni++) rB[ni] = *(const short8*)&Bc[boff[ni]];

#pragma unroll 1
  for (int kt = 0; kt < 64; ++kt) {
    if (kt < 62) {
#pragma unroll
      for (int c = 0; c < 4; c++) { gload16(ga[c], Ag + c * 4096 + sd); ga[c] += 64; }
#pragma unroll
      for (int c = 0; c < 2; c++) { gload16(gb[c], Bg + c * 4096 + sd); gb[c] += 64; }
    }
#pragma unroll
    for (int mi = 0; mi < 4; mi++) sA[mi] = *(const short8*)&Ac[aoff[mi] ^ 32];
#pragma unroll
    for (int ni = 0; ni < 4; ni++) sB[ni] = *(const short8*)&Bc[boff[ni] ^ 32];
    __builtin_amdgcn_sched_barrier(0);
    __builtin_amdgcn_s_setprio(1);
#pragma unroll
    for (int mi = 0; mi < 4; mi++)
#pragma unroll
      for (int ni = 0; ni < 4; ni++)
        acc[mi][ni] = MFMA_BF16(rA[mi], rB[ni], acc[mi][ni]);
    __builtin_amdgcn_s_setprio(0);
    asm volatile("s_waitcnt lgkmcnt(0)" ::: "memory");
    __builtin_amdgcn_sched_barrier(0);
    if (kt < 62)       asm volatile("s_waitcnt vmcnt(6)" ::: "memory");
    else if (kt == 62) asm volatile("s_waitcnt vmcnt(0)" ::: "memory");
    if (kt < 63) __builtin_amdgcn_s_barrier();
    __builtin_amdgcn_sched_barrier(0);
    if (kt < 63) {
#pragma unroll
      for (int mi = 0; mi < 4; mi++) rA[mi] = *(const short8*)&An[aoff[mi]];
#pragma unroll
      for (int ni = 0; ni < 4; ni++) rB[ni] = *(const short8*)&Bn[boff[ni]];
    }
    __builtin_amdgcn_sched_barrier(0);
    __builtin_amdgcn_s_setprio(1);
#pragma unroll
    for (int mi = 0; mi < 4; mi++)
#pragma unroll
      for (int ni = 0; ni < 4; ni++)
        acc[mi][ni] = MFMA_BF16(sA[mi], sB[ni], acc[mi][ni]);
    __builtin_amdgcn_s_setprio(0);
    const bf16_t* ta = Ac; Ac = An; An = Ag; Ag = (bf16_t*)ta;
    const bf16_t* tb = Bc; Bc = Bn; Bn = Bg; Bg = (bf16_t*)tb;
  }

#pragma unroll
  for (int mi = 0; mi < 4; mi++) {
#pragma unroll
    for (int ni = 0; ni < 4; ni++) {
      const int row = m0 + WM + mi * 16 + quad * 4;
      const int col = n0 + WN + ni * 16 + l16;
      const float bb = bias[col];
#pragma unroll
      for (int r = 0; r < 4; r++)
        out[(size_t)(row + r) * HDIM + col] = acc[mi][ni][r] + bb;
    }
  }
}

// ---------------------------------------------------------------- launch

extern "C" void kernel_launch(void* const* d_in, const int* in_sizes, int n_in,
                              void* d_out, int out_size, void* d_ws, size_t ws_size,
                              hipStream_t stream) {
  const float* x   = (const float*)d_in[0];
  const float* rw  = (const float*)d_in[1];
  const float* rb  = (const float*)d_in[2];
  const float* w1  = (const float*)d_in[3];
  const float* w2  = (const float*)d_in[4];
  const float* l2w = (const float*)d_in[5];
  const float* l2b = (const float*)d_in[6];

  char* ws = (char*)d_ws;
  int*    ctrl     = (int*)   (ws + 0);
  int*    gid_tok  = (int*)   (ws + 4096);
  float2* tokscale = (float2*)(ws + 36864);
  int*    tokslot  = (int*)   (ws + 102400);
  float2* slotsc   = (float2*)(ws + 167936);
  bf16_t* xb  = (bf16_t*)(ws + 1048576);        // 16.78 MB
  bf16_t* w1p = (bf16_t*)(ws + 17825792);       //  4.19 MB (128 images)
  bf16_t* w2p = (bf16_t*)(ws + 22020096);       // 16.78 MB (1024 BLKs)
  bf16_t* ltw = (bf16_t*)(ws + 38797312);       //  8.39 MB (row-major [h][f])
  bf16_t* Tp  = (bf16_t*)(ws + 47185920);       // 12.58 MB (96 tiles x 8 BLKs)
  bf16_t* Hb  = (bf16_t*)(ws + 59768832);       // 67.11 MB -> end 126,877,696

  router_kernel<<<TOK / 4, 256, 0, stream>>>(x, rw, rb, gid_tok, tokscale, xb);
  build_tiles<<<1, 256, 0, stream>>>(gid_tok, ctrl, tokslot, slotsc);
  scatter_tokens<<<TOK / 256, 256, 0, stream>>>(gid_tok, tokscale, ctrl, tokslot, slotsc);

  pack_w1<<<128, 256, 0, stream>>>(w1, w1p);
  pack_w2<<<1024, 256, 0, stream>>>(w2, w2p);
  tcvt<<<dim3(HDIM / 64, FDIM / 64, 1), dim3(64, 4), 0, stream>>>(
      l2w, ltw, HDIM, 0, FDIM, 0, 0);

  gemm_g1<<<8 * MAXTILES, 256, 0, stream>>>(xb, w1p, Tp, ctrl, tokslot, slotsc);
  gemm_g2<<<8 * MAXTILES, 256, 0, stream>>>(Tp, w2p, Hb, ctrl, tokslot);
  gemm_g3<<<256, 512, 0, stream>>>(Hb, ltw, (float*)d_out, l2b);
}

// Round 10
// 341.457 us; speedup vs baseline: 1.2158x; 1.2158x over previous
//
#include <hip/hip_runtime.h>
#include <math.h>

// MoE FFN, routed (top-2 pair-grouped).
//   Tp (G1 out / G2 A): per tile, 8 sequential 16-KB BLK blocks
//       BLK = [128 rows][64 k], elem(r,k) at r*64+(((k>>3)^(r&7))<<3|(k&7)).
//       kt = esel*4 + rb  (rank = rb*64 + klocal).  mh half = rows 64.. =
//       second 8 KB of a BLK (row-major in 64-elem rows).
//   w2p: BLK blocks [nb128(32)][e(8)][rb(4)], rows = f-local, k = rank-local.
//   Hb (G2 out / G3 A): plain row-major [tok][4096].
//   G1: 64x128 BK=128 (2-barrier main loop; epilogue -> BLKs)
//   G2: round-14: REVERT to the r4 2-barrier structure (72 us, best of all
//       G2 variants; every pipelined rebuild was worse: 93/100/112/158 us —
//       for 8-MFLOP blocks, 3-blocks/CU TLP beats intra-block pipelining).
//       Adapted to BLK operands (linear staging) + r11-verified XOR-slot
//       epilogue (kills r4's 1.15M bank conflicts).
//   G3: round-8 (verified): BM=256 BN=128 BK=64, 8 waves, 3-stage pipeline.
// Image swizzle (G1 inputs only): r*128 + (((k>>3)^(r&15))<<3 | (k&7)).

using short8  = __attribute__((ext_vector_type(8))) short;
using floatx4 = __attribute__((ext_vector_type(4))) float;
typedef unsigned short bf16_t;

#define TOK   8192
#define HDIM  1024
#define RDIM  256
#define FDIM  4096
#define NEXP  8
#define MAXTILES 96
#define MAXSLOTS 16384
#define IMG   16384

__device__ __forceinline__ bf16_t f2bf(float f) {
  union { float f; unsigned u; } a; a.f = f;
  unsigned u = a.u;
  return (bf16_t)((u + 0x7FFFu + ((u >> 16) & 1u)) >> 16);  // RNE
}

__device__ __forceinline__ float gelu_erf(float v) {
  return 0.5f * v * (1.0f + erff(v * 0.70710678118654752f));
}

__device__ __forceinline__ void gload16(const void* g, void* l) {
  __builtin_amdgcn_global_load_lds(
      (const __attribute__((address_space(1))) void*)g,
      (__attribute__((address_space(3))) void*)l, 16, 0, 0);
}

__device__ __forceinline__ int swz_off(int r, int kl) {
  return r * 128 + ((((kl >> 3) ^ (r & 15)) << 3) | (kl & 7));
}

// ---------------------------------------------------------------- packing

__device__ __forceinline__ void pack_tile_body(const float* __restrict__ src,
                                               size_t kStride,
                                               bf16_t* __restrict__ img) {
  __shared__ bf16_t lim[IMG];
  const int tid = threadIdx.x;
  const int rr = tid & 127, half = tid >> 7;
  for (int kl = half; kl < 128; kl += 2)
    lim[swz_off(rr, kl)] = f2bf(src[(size_t)kl * kStride + rr]);
  __syncthreads();
  const int4* s4 = (const int4*)lim;
  int4* d4 = (int4*)img;
#pragma unroll
  for (int i = 0; i < 8; i++) d4[tid + i * 256] = s4[tid + i * 256];
}

// w1p [e][nc][kb]: rows = rank nc*128+rr, k = h kb*128+kl  (G1 B operand)
__global__ void pack_w1(const float* __restrict__ w1, bf16_t* __restrict__ w1p) {
  const int img = blockIdx.x;
  const int e = img >> 4, nc = (img >> 3) & 1, kb = img & 7;
  pack_tile_body(w1 + (size_t)e * 1024 * 256 + (size_t)kb * 128 * 256 + nc * 128,
                 256, w1p + (size_t)img * IMG);
}

// w2p: BLK blocks [nb128][e][rb]: 128 f-rows x 64 rank, G3-style swizzle.
__global__ void pack_w2(const float* __restrict__ w2, bf16_t* __restrict__ w2p) {
  __shared__ bf16_t lim[8192];
  const int img = blockIdx.x;                // nb*32 + e*4 + rb
  const int nb = img >> 5, e = (img >> 2) & 7, rb = img & 3;
  const float* src = w2 + (size_t)e * 256 * 4096 + (size_t)rb * 64 * 4096 + nb * 128;
  const int tid = threadIdx.x;
  const int row = tid & 127, k0 = tid >> 7;  // k0 = 0/1
  for (int k = k0; k < 64; k += 2)
    lim[row * 64 + ((((k >> 3) ^ (row & 7)) << 3) | (k & 7))] =
        f2bf(src[(size_t)k * 4096 + row]);
  __syncthreads();
  const int4* s4 = (const int4*)lim;
  int4* d4 = (int4*)(w2p + (size_t)img * 8192);
#pragma unroll
  for (int i = 0; i < 4; i++) d4[tid + i * 256] = s4[tid + i * 256];
}

// transpose+convert (for lin2_w -> ltw[h][f], row-major bf16)
__global__ void tcvt(const float* __restrict__ in, bf16_t* __restrict__ out,
                     int cols, size_t inSlice, size_t ldo,
                     int outRowStep, int outColStep) {
  __shared__ float tile[64][65];
  const int z  = blockIdx.z;
  const float* src = in + (size_t)z * inSlice;
  const int c0 = blockIdx.x * 64;
  const int r0 = blockIdx.y * 64;
  const int tx = threadIdx.x;
  const int ty = threadIdx.y;
#pragma unroll
  for (int i = 0; i < 64; i += 4)
    tile[ty + i][tx] = src[(size_t)(r0 + ty + i) * cols + (c0 + tx)];
  __syncthreads();
#pragma unroll
  for (int i = 0; i < 64; i += 4) {
    float v = tile[tx][ty + i];
    out[((size_t)(c0 + ty + i) + (size_t)z * outRowStep) * ldo +
        (size_t)z * outColStep + (r0 + tx)] = f2bf(v);
  }
}

// ---------------------------------------------------------------- routing

__global__ void router_kernel(const float* __restrict__ x,
                              const float* __restrict__ rw,
                              const float* __restrict__ rb,
                              int* __restrict__ gid_tok,
                              float2* __restrict__ tokscale,
                              bf16_t* __restrict__ xb) {
  const int token = blockIdx.x * 4 + (threadIdx.x >> 6);
  const int lane  = threadIdx.x & 63;
  const float* xr = x + (size_t)token * HDIM;
  bf16_t* xbr = xb + (size_t)token * HDIM;

  double acc[NEXP];
#pragma unroll
  for (int e = 0; e < NEXP; e++) acc[e] = 0.0;
  for (int h = lane; h < HDIM; h += 64) {
    const float xf = xr[h];
    xbr[h] = f2bf(xf);
    const double xv = (double)xf;
    const float* wr = rw + (size_t)h * NEXP;
#pragma unroll
    for (int e = 0; e < NEXP; e++) acc[e] += xv * (double)wr[e];
  }
#pragma unroll
  for (int off = 32; off > 0; off >>= 1) {
#pragma unroll
    for (int e = 0; e < NEXP; e++) acc[e] += __shfl_xor(acc[e], off, 64);
  }
  double lg[NEXP];
#pragma unroll
  for (int e = 0; e < NEXP; e++) lg[e] = acc[e] + (double)rb[e];

  double mx = lg[0];
#pragma unroll
  for (int e = 1; e < NEXP; e++) mx = fmax(mx, lg[e]);
  double p[NEXP]; double den = 0.0;
#pragma unroll
  for (int e = 0; e < NEXP; e++) { p[e] = exp(lg[e] - mx); den += p[e]; }

  int i1 = 0;
#pragma unroll
  for (int e = 1; e < NEXP; e++) if (lg[e] > lg[i1]) i1 = e;
  int i2 = (i1 == 0) ? 1 : 0;
#pragma unroll
  for (int e = 0; e < NEXP; e++)
    if (e != i1 && e != i2 && lg[e] > lg[i2]) i2 = e;

  if (lane == 0) {
    const int elo = min(i1, i2), ehi = max(i1, i2);
    gid_tok[token] = elo * 8 + ehi;
    tokscale[token] = make_float2((float)(p[elo] / den), (float)(p[ehi] / den));
  }
}

__global__ void build_tiles(const int* __restrict__ gid_tok,
                            int* __restrict__ ctrl,
                            int* __restrict__ tok_of_slot,
                            float2* __restrict__ scale_of_slot) {
  __shared__ int hist[64], ntl[64];
  const int t = threadIdx.x;
  for (int i = t; i < MAXSLOTS; i += 256) {
    tok_of_slot[i] = -1;
    scale_of_slot[i] = make_float2(0.f, 0.f);
  }
  if (t < 64) hist[t] = 0;
  __syncthreads();
  for (int i = t; i < TOK; i += 256) atomicAdd(&hist[gid_tok[i]], 1);
  __syncthreads();
  if (t < 64) ntl[t] = (hist[t] + 127) >> 7;
  __syncthreads();
  if (t < 64) {
    int slot0 = 0, tile0 = 0;
    for (int g = 0; g < t; g++) { slot0 += ntl[g] << 7; tile0 += ntl[g]; }
    ctrl[64 + t] = 0;
    ctrl[128 + t] = slot0;
    const int nt = ntl[t], c = hist[t];
    for (int i = 0; i < nt; i++) {
      ctrl[256 + (tile0 + i) * 3 + 0] = t;
      ctrl[256 + (tile0 + i) * 3 + 1] = slot0 + i * 128;
      ctrl[256 + (tile0 + i) * 3 + 2] = min(128, c - i * 128);
    }
    if (t == 63) ctrl[192] = tile0 + nt;
  }
}

__global__ void scatter_tokens(const int* __restrict__ gid_tok,
                               const float2* __restrict__ tokscale,
                               int* __restrict__ ctrl,
                               int* __restrict__ tok_of_slot,
                               float2* __restrict__ scale_of_slot) {
  const int t = blockIdx.x * 256 + threadIdx.x;
  const int g = gid_tok[t];
  const int pos = atomicAdd(&ctrl[64 + g], 1);
  const int slot = ctrl[128 + g] + pos;
  tok_of_slot[slot] = t;
  scale_of_slot[slot] = tokscale[t];
}

// ---------------------------------------------------------------- G1
// 64x128 tile, BK=128. Main loop unchanged. Epilogue writes Tp BLKs:
// kt = n*2 + (c>>6); elem at BLKbase + row*64 + (((c>>3&7)^(row&7))<<3|(c&7)).
__global__ __launch_bounds__(256)
void gemm_g1(const bf16_t* __restrict__ xb, const bf16_t* __restrict__ w1p,
             bf16_t* __restrict__ Tp, const int* __restrict__ ctrl,
             const int* __restrict__ tok_of_slot,
             const float2* __restrict__ scale_of_slot) {
  const int b = blockIdx.x;
  const int tile = b >> 3, mh = (b >> 2) & 1, n = b & 3;
  if (tile >= ctrl[192]) return;
  const int nrows = ctrl[256 + tile * 3 + 2];
  if (mh && nrows <= 64) return;
  __shared__ bf16_t As[64 * 128];
  __shared__ bf16_t Bs[128 * 128];
  const int gid   = ctrl[256 + tile * 3];
  const int slot0 = ctrl[256 + tile * 3 + 1];
  const int e = (n < 2) ? (gid >> 3) : (gid & 7);
  const int nc = n & 1;
  const int tid = threadIdx.x, lane = tid & 63, w = tid >> 6;
  const int wm = (w & 1) * 32, wn = (w >> 1) * 64;
  const int l16 = lane & 15, quad = lane >> 4;

  floatx4 acc[2][4];
  const floatx4 zero = {0.f, 0.f, 0.f, 0.f};
#pragma unroll
  for (int i = 0; i < 2; i++)
#pragma unroll
    for (int j = 0; j < 4; j++) acc[i][j] = zero;

  int toks[4];
  int rowAs[4];
#pragma unroll
  for (int i = 0; i < 4; i++) {
    rowAs[i] = w * 16 + i * 4 + (lane >> 4);
    int tk = tok_of_slot[slot0 + mh * 64 + rowAs[i]];
    toks[i] = (tk < 0) ? 0 : tk;
  }
  const bf16_t* bimg = w1p + (size_t)(e * 16 + nc * 8) * IMG;
  bf16_t* lA = As + w * 2048;
  bf16_t* lB = Bs + w * 4096;

  for (int kb = 0; kb < 8; kb++) {
    __syncthreads();
#pragma unroll
    for (int i = 0; i < 4; i++) {
      const int gq = (lane & 15) ^ (rowAs[i] & 15);
      gload16(xb + (size_t)toks[i] * HDIM + kb * 128 + gq * 8, lA + i * 512);
    }
#pragma unroll
    for (int i = 0; i < 8; i++)
      gload16(bimg + (size_t)kb * IMG + w * 4096 + i * 512 + lane * 8, lB + i * 512);
    __syncthreads();
#pragma unroll
    for (int s = 0; s < 4; s++) {
      const int pg = ((s * 4 + quad) ^ l16) << 3;
      short8 af[2], bfr[4];
#pragma unroll
      for (int i = 0; i < 2; i++)
        af[i] = *(const short8*)&As[(wm + i * 16 + l16) * 128 + pg];
#pragma unroll
      for (int i = 0; i < 4; i++)
        bfr[i] = *(const short8*)&Bs[(wn + i * 16 + l16) * 128 + pg];
#pragma unroll
      for (int mi = 0; mi < 2; mi++)
#pragma unroll
        for (int ni = 0; ni < 4; ni++)
          acc[mi][ni] = __builtin_amdgcn_mfma_f32_16x16x32_bf16(
              af[mi], bfr[ni], acc[mi][ni], 0, 0, 0);
    }
  }

  // epilogue: scaled bf16 -> BLK-layout LDS -> two 8-KB chunks to Tp
  __syncthreads();
#pragma unroll
  for (int mi = 0; mi < 2; mi++) {
#pragma unroll
    for (int r = 0; r < 4; r++) {
      const int rloc = wm + mi * 16 + quad * 4 + r;
      const float2 sc = scale_of_slot[slot0 + mh * 64 + rloc];
      const float s = (n < 2) ? sc.x : sc.y;
#pragma unroll
      for (int ni = 0; ni < 4; ni++) {
        const int c = wn + ni * 16 + l16;
        As[((c >> 6) << 12) + rloc * 64 +
           (((((c >> 3) & 7) ^ (rloc & 7)) << 3) | (c & 7))] =
            f2bf(acc[mi][ni][r] * s);
      }
    }
  }
  __syncthreads();
  {
    const int4* s4 = (const int4*)As;
    int4* d0 = (int4*)(Tp + (size_t)tile * 65536 + (size_t)(n * 2) * 8192 + mh * 4096);
    int4* d1 = (int4*)(Tp + (size_t)tile * 65536 + (size_t)(n * 2 + 1) * 8192 + mh * 4096);
    d0[tid] = s4[tid];
    d0[tid + 256] = s4[tid + 256];
    d1[tid] = s4[tid + 512];
    d1[tid + 256] = s4[tid + 768];
  }
}

// ---------------------------------------------------------------- G2
// Round-14: r4 structure (2-barrier lockstep, 48 KB -> 3 blocks/CU, best
// measured G2 at 72 us) on BLK operands. 64x128 out/block, 4 waves (2Mx2N),
// 4 t-iters: t -> (expert esel=t>>1, rank half rb0=(t&1)*2). Per t: stage
// A 16 KB (two Tp BLK mh-halves, linear) + B 32 KB (two w2p BLKs, linear),
// 2 barriers, 4 K-slices x 8 MFMA. Epilogue: r11-verified XOR-slot LDS
// (conflict-free; r4's row*128 epilogue cost 1.15M bank conflicts).
#define MFMA_BF16(a, b, c) __builtin_amdgcn_mfma_f32_16x16x32_bf16(a, b, c, 0, 0, 0)

__global__ __launch_bounds__(256)
void gemm_g2(const bf16_t* __restrict__ Tp, const bf16_t* __restrict__ w2p,
             bf16_t* __restrict__ Hb, const int* __restrict__ ctrl,
             const int* __restrict__ tok_of_slot) {
  __shared__ bf16_t As[8192];     // 16 KB: BLK-pair mh-halves
  __shared__ bf16_t Bs[16384];    // 32 KB: two w2p BLKs
  const int b = blockIdx.x;
  const int tile = b >> 6, mh = (b >> 5) & 1, n = b & 31;
  if (tile >= ctrl[192]) return;
  const int nrows = ctrl[256 + tile * 3 + 2];
  if (mh && nrows <= 64) return;
  const int gid   = ctrl[256 + tile * 3];
  const int slot0 = ctrl[256 + tile * 3 + 1];
  const int elo = gid >> 3, ehi = gid & 7;

  const int tid = threadIdx.x, lane = tid & 63, w = tid >> 6;
  const int l16 = lane & 15, quad = lane >> 4;
  const int wm = (w & 1) * 32, wn = (w >> 1) * 64;

  floatx4 acc[2][4];
  const floatx4 zero = {0.f, 0.f, 0.f, 0.f};
#pragma unroll
  for (int i = 0; i < 2; i++)
#pragma unroll
    for (int j = 0; j < 4; j++) acc[i][j] = zero;

  const bf16_t* Abase = Tp + (size_t)tile * 65536 + mh * 4096;

#pragma unroll
  for (int t = 0; t < 4; t++) {
    const int e   = (t < 2) ? elo : ehi;
    const int rb0 = (t & 1) * 2;
    __syncthreads();
    // A: two BLK mh-halves (8 KB each), linear; waves 0,1 -> BLK(t*2),
    // waves 2,3 -> BLK(t*2+1). 4 insts/thread.
#pragma unroll
    for (int i = 0; i < 4; i++)
      gload16(Abase + (size_t)(t * 2 + (w >> 1)) * 8192 +
                  (w & 1) * 2048 + i * 512 + lane * 8,
              As + w * 2048 + i * 512);
    // B: two w2p BLKs (16 KB each), linear; waves 0,1 -> rb0, 2,3 -> rb0+1.
#pragma unroll
    for (int i = 0; i < 8; i++)
      gload16(w2p + (size_t)(n * 32 + e * 4 + rb0 + (w >> 1)) * 8192 +
                  (w & 1) * 4096 + i * 512 + lane * 8,
              Bs + w * 4096 + i * 512);
    __syncthreads();
#pragma unroll
    for (int s = 0; s < 4; s++) {
      short8 af[2], bfr[4];
#pragma unroll
      for (int mi = 0; mi < 2; mi++) {
        const int r = wm + mi * 16 + l16;
        af[mi] = *(const short8*)
            &As[(s >> 1) * 4096 + r * 64 +
                ((((s & 1) * 4 + quad) ^ (r & 7)) << 3)];
      }
#pragma unroll
      for (int ni = 0; ni < 4; ni++) {
        const int r = wn + ni * 16 + l16;
        bfr[ni] = *(const short8*)
            &Bs[(s >> 1) * 8192 + r * 64 +
                ((((s & 1) * 4 + quad) ^ (r & 7)) << 3)];
      }
#pragma unroll
      for (int mi = 0; mi < 2; mi++)
#pragma unroll
        for (int ni = 0; ni < 4; ni++)
          acc[mi][ni] = MFMA_BF16(af[mi], bfr[ni], acc[mi][ni]);
    }
  }

  // epilogue: gelu -> XOR-slot LDS [64][128] (conflict-free) -> token scatter
  __syncthreads();
#pragma unroll
  for (int mi = 0; mi < 2; mi++)
#pragma unroll
    for (int ni = 0; ni < 4; ni++) {
#pragma unroll
      for (int r = 0; r < 4; r++) {
        const int row = wm + mi * 16 + quad * 4 + r;
        const int col = wn + ni * 16 + l16;
        Bs[row * 128 + (col ^ (((row >> 2) & 3) << 4))] =
            f2bf(gelu_erf(acc[mi][ni][r]));
      }
    }
  __syncthreads();
  const int4* s4 = (const int4*)Bs;
#pragma unroll
  for (int j4 = 0; j4 < 4; j4++) {
    const int chunk = tid + j4 * 256;
    const int row = chunk >> 4, off = chunk & 15;
    const int tok = tok_of_slot[slot0 + mh * 64 + row];
    if (tok >= 0)
      *(int4*)(Hb + (size_t)tok * FDIM + n * 128 + off * 8) =
          s4[(row << 4) | (off ^ (((row >> 2) & 3) << 1))];
  }
}

// ---------------------------------------------------------------- G3
// Round-8 (verified): BM=256 BN=128 BK=64, 512 threads = 8 waves (4Mx2N),
// 64x64/wave, 3-stage pipeline, counted vmcnt(6), triple-buffer 144 KB.
__global__ __launch_bounds__(512, 1)
void gemm_g3(const bf16_t* __restrict__ Hb, const bf16_t* __restrict__ ltw,
             float* __restrict__ out, const float* __restrict__ bias) {
  __shared__ bf16_t As[3 * 256 * 64];   // 96 KB
  __shared__ bf16_t Bs[3 * 128 * 64];   // 48 KB

  const int i = blockIdx.x;
  const int xcd = i & 7, j = i >> 3;
  const int m0 = (xcd * 4 + (j >> 3)) * 256;
  const int n0 = (j & 7) * 128;

  const int tid  = threadIdx.x;
  const int lane = tid & 63;
  const int w    = tid >> 6;
  const int l16  = lane & 15;
  const int quad = (lane >> 4) & 3;
  const int WM   = (w & 3) * 64;
  const int WN   = (w >> 2) * 64;

  const int srow = tid >> 3;
  const int sswz = ((tid & 7) ^ (srow & 7)) << 3;
  const bf16_t* ga[4];
  const bf16_t* gb[2];
#pragma unroll
  for (int c = 0; c < 4; c++)
    ga[c] = Hb + (size_t)(m0 + c * 64 + srow) * FDIM + sswz;
#pragma unroll
  for (int c = 0; c < 2; c++)
    gb[c] = ltw + (size_t)(n0 + c * 64 + srow) * FDIM + sswz;
  const int sd = w * 512;

  int aoff[4], boff[4];
#pragma unroll
  for (int mi = 0; mi < 4; mi++) {
    const int r = WM + mi * 16 + l16;
    aoff[mi] = r * 64 + (((((r >> 2) & 1) << 2) | (quad ^ (r & 3))) << 3);
  }
#pragma unroll
  for (int ni = 0; ni < 4; ni++) {
    const int r = WN + ni * 16 + l16;
    boff[ni] = r * 64 + (((((r >> 2) & 1) << 2) | (quad ^ (r & 3))) << 3);
  }

  floatx4 acc[4][4];
  const floatx4 zero = {0.f, 0.f, 0.f, 0.f};
#pragma unroll
  for (int mi = 0; mi < 4; mi++)
#pragma unroll
    for (int ni = 0; ni < 4; ni++) acc[mi][ni] = zero;

  const bf16_t* Ac = As;              const bf16_t* Bc = Bs;
  const bf16_t* An = As + 16384;      const bf16_t* Bn = Bs + 8192;
  bf16_t*       Ag = As + 32768;      bf16_t*       Bg = Bs + 16384;

#pragma unroll
  for (int c = 0; c < 4; c++) { gload16(ga[c], (bf16_t*)As + c * 4096 + sd); ga[c] += 64; }
#pragma unroll
  for (int c = 0; c < 2; c++) { gload16(gb[c], (bf16_t*)Bs + c * 4096 + sd); gb[c] += 64; }
#pragma unroll
  for (int c = 0; c < 4; c++) { gload16(ga[c], (bf16_t*)As + 16384 + c * 4096 + sd); ga[c] += 64; }
#pragma unroll
  for (int c = 0; c < 2; c++) { gload16(gb[c], (bf16_t*)Bs + 8192 + c * 4096 + sd); gb[c] += 64; }
  asm volatile("s_waitcnt vmcnt(6)" ::: "memory");
  __builtin_amdgcn_s_barrier();

  short8 rA[4], rB[4], sA[4], sB[4];
#pragma unroll
  for (int mi = 0; mi < 4; mi++) rA[mi] = *(const short8*)&Ac[aoff[mi]];
#pragma unroll
  for (int ni = 0; ni < 4; ni++) rB[ni] = *(const short8*)&Bc[boff[ni]];

#pragma unroll 1
  for (int kt = 0; kt < 64; ++kt) {
    if (kt < 62) {
#pragma unroll
      for (int c = 0; c < 4; c++) { gload16(ga[c], Ag + c * 4096 + sd); ga[c] += 64; }
#pragma unroll
      for (int c = 0; c < 2; c++) { gload16(gb[c], Bg + c * 4096 + sd); gb[c] += 64; }
    }
#pragma unroll
    for (int mi = 0; mi < 4; mi++) sA[mi] = *(const short8*)&Ac[aoff[mi] ^ 32];
#pragma unroll
    for (int ni = 0; ni < 4; ni++) sB[ni] = *(const short8*)&Bc[boff[ni] ^ 32];
    __builtin_amdgcn_sched_barrier(0);
    __builtin_amdgcn_s_setprio(1);
#pragma unroll
    for (int mi = 0; mi < 4; mi++)
#pragma unroll
      for (int ni = 0; ni < 4; ni++)
        acc[mi][ni] = MFMA_BF16(rA[mi], rB[ni], acc[mi][ni]);
    __builtin_amdgcn_s_setprio(0);
    asm volatile("s_waitcnt lgkmcnt(0)" ::: "memory");
    __builtin_amdgcn_sched_barrier(0);
    if (kt < 62)       asm volatile("s_waitcnt vmcnt(6)" ::: "memory");
    else if (kt == 62) asm volatile("s_waitcnt vmcnt(0)" ::: "memory");
    if (kt < 63) __builtin_amdgcn_s_barrier();
    __builtin_amdgcn_sched_barrier(0);
    if (kt < 63) {
#pragma unroll
      for (int mi = 0; mi < 4; mi++) rA[mi] = *(const short8*)&An[aoff[mi]];
#pragma unroll
      for (int ni = 0; ni < 4; ni++) rB[ni] = *(const short8*)&Bn[boff[ni]];
    }
    __builtin_amdgcn_sched_barrier(0);
    __builtin_amdgcn_s_setprio(1);
#pragma unroll
    for (int mi = 0; mi < 4; mi++)
#pragma unroll
      for (int ni = 0; ni < 4; ni++)
        acc[mi][ni] = MFMA_BF16(sA[mi], sB[ni], acc[mi][ni]);
    __builtin_amdgcn_s_setprio(0);
    const bf16_t* ta = Ac; Ac = An; An = Ag; Ag = (bf16_t*)ta;
    const bf16_t* tb = Bc; Bc = Bn; Bn = Bg; Bg = (bf16_t*)tb;
  }

#pragma unroll
  for (int mi = 0; mi < 4; mi++) {
#pragma unroll
    for (int ni = 0; ni < 4; ni++) {
      const int row = m0 + WM + mi * 16 + quad * 4;
      const int col = n0 + WN + ni * 16 + l16;
      const float bb = bias[col];
#pragma unroll
      for (int r = 0; r < 4; r++)
        out[(size_t)(row + r) * HDIM + col] = acc[mi][ni][r] + bb;
    }
  }
}

// ---------------------------------------------------------------- launch

extern "C" void kernel_launch(void* const* d_in, const int* in_sizes, int n_in,
                              void* d_out, int out_size, void* d_ws, size_t ws_size,
                              hipStream_t stream) {
  const float* x   = (const float*)d_in[0];
  const float* rw  = (const float*)d_in[1];
  const float* rb  = (const float*)d_in[2];
  const float* w1  = (const float*)d_in[3];
  const float* w2  = (const float*)d_in[4];
  const float* l2w = (const float*)d_in[5];
  const float* l2b = (const float*)d_in[6];

  char* ws = (char*)d_ws;
  int*    ctrl     = (int*)   (ws + 0);
  int*    gid_tok  = (int*)   (ws + 4096);
  float2* tokscale = (float2*)(ws + 36864);
  int*    tokslot  = (int*)   (ws + 102400);
  float2* slotsc   = (float2*)(ws + 167936);
  bf16_t* xb  = (bf16_t*)(ws + 1048576);        // 16.78 MB
  bf16_t* w1p = (bf16_t*)(ws + 17825792);       //  4.19 MB (128 images)
  bf16_t* w2p = (bf16_t*)(ws + 22020096);       // 16.78 MB (1024 BLKs)
  bf16_t* ltw = (bf16_t*)(ws + 38797312);       //  8.39 MB (row-major [h][f])
  bf16_t* Tp  = (bf16_t*)(ws + 47185920);       // 12.58 MB (96 tiles x 8 BLKs)
  bf16_t* Hb  = (bf16_t*)(ws + 59768832);       // 67.11 MB -> end 126,877,696

  router_kernel<<<TOK / 4, 256, 0, stream>>>(x, rw, rb, gid_tok, tokscale, xb);
  build_tiles<<<1, 256, 0, stream>>>(gid_tok, ctrl, tokslot, slotsc);
  scatter_tokens<<<TOK / 256, 256, 0, stream>>>(gid_tok, tokscale, ctrl, tokslot, slotsc);

  pack_w1<<<128, 256, 0, stream>>>(w1, w1p);
  pack_w2<<<1024, 256, 0, stream>>>(w2, w2p);
  tcvt<<<dim3(HDIM / 64, FDIM / 64, 1), dim3(64, 4), 0, stream>>>(
      l2w, ltw, HDIM, 0, FDIM, 0, 0);

  gemm_g1<<<8 * MAXTILES, 256, 0, stream>>>(xb, w1p, Tp, ctrl, tokslot, slotsc);
  gemm_g2<<<64 * MAXTILES, 256, 0, stream>>>(Tp, w2p, Hb, ctrl, tokslot);
  gemm_g3<<<256, 512, 0, stream>>>(Hb, ltw, (float*)d_out, l2b);
}